// Round 1
// baseline (64.429 us; speedup 1.0000x reference)
//
#include <hip/hip_runtime.h>

// HungarianMatcher cost matrix:
//   C[n,m] = (1 - sigmoid(cls_boxes[n, cls_targets[m]-1]))     // class cost
//          + sum_k |pred_boxes[n,k] - tgt_boxes[m,k]|           // L1 box cost
//          - IoU(pred_boxes[n], tgt_boxes[m])                   // neg IoU cost
//
// N=16384 preds, M=2048 targets, NCLS=40. Output 128 MiB fp32 -> write-bound.
// One thread computes 4 consecutive columns (float4 store, 16 B/lane).

#define NPRED 16384
#define NTGT  2048
#define NCLS  40

__global__ __launch_bounds__(256) void matcher_cost_kernel(
    const float* __restrict__ cls_boxes,    // [NPRED, NCLS]
    const int*   __restrict__ cls_targets,  // [NTGT]
    const float4* __restrict__ pred_boxes,  // [NPRED] (x1,y1,x2,y2)
    const float4* __restrict__ tgt_boxes,   // [NTGT]
    float* __restrict__ out)                // [NPRED, NTGT]
{
    const int M4 = NTGT / 4;                        // 512 float4-groups per row
    int idx = blockIdx.x * blockDim.x + threadIdx.x; // one thread = 4 outputs
    int n  = idx / M4;
    int m4 = idx - n * M4;
    if (n >= NPRED) return;

    float4 pb = pred_boxes[n];                      // wave-mostly-uniform, L1 hit
    float area1 = (pb.z - pb.x) * (pb.w - pb.y);
    const float* clsrow = cls_boxes + n * NCLS;     // 160 B row, L1-resident

    int mbase = m4 * 4;
    float4 res;
    float* r = &res.x;
    #pragma unroll
    for (int j = 0; j < 4; ++j) {
        int m = mbase + j;
        float4 tb = tgt_boxes[m];                   // 32 KB total, L1/L2-resident
        float area2 = (tb.z - tb.x) * (tb.w - tb.y);

        // IoU
        float lx = fmaxf(pb.x, tb.x);
        float ly = fmaxf(pb.y, tb.y);
        float rx = fminf(pb.z, tb.z);
        float ry = fminf(pb.w, tb.w);
        float w  = fmaxf(rx - lx, 0.0f);
        float h  = fmaxf(ry - ly, 0.0f);
        float ov = w * h;
        float uni = fmaxf(area1 + area2 - ov, 1e-6f);
        float iou = ov / uni;

        // L1 (cdist p=1)
        float l1 = fabsf(pb.x - tb.x) + fabsf(pb.y - tb.y)
                 + fabsf(pb.z - tb.z) + fabsf(pb.w - tb.w);

        // class cost: 1 - sigmoid(x) = 1/(1 + e^x)
        int c = cls_targets[m] - 1;                 // labels are 1..NCLS
        float logit = clsrow[c];
        float ccls = 1.0f / (1.0f + __expf(logit));

        r[j] = ccls + l1 - iou;
    }
    *reinterpret_cast<float4*>(out + (size_t)n * NTGT + mbase) = res;
}

extern "C" void kernel_launch(void* const* d_in, const int* in_sizes, int n_in,
                              void* d_out, int out_size, void* d_ws, size_t ws_size,
                              hipStream_t stream) {
    const float*  cls_boxes   = (const float*)d_in[0];
    const int*    cls_targets = (const int*)d_in[1];
    const float4* pred_boxes  = (const float4*)d_in[2];
    const float4* tgt_boxes   = (const float4*)d_in[3];
    float* out = (float*)d_out;

    const int total_threads = NPRED * (NTGT / 4);   // 8.4M threads
    const int block = 256;
    const int grid = (total_threads + block - 1) / block; // 32768 blocks

    matcher_cost_kernel<<<grid, block, 0, stream>>>(
        cls_boxes, cls_targets, pred_boxes, tgt_boxes, out);
}

// Round 2
// 32.266 us; speedup vs baseline: 1.9968x; 1.9968x over previous
//
#include <hip/hip_runtime.h>

// HungarianMatcher cost matrix:
//   C[n,m] = (1 - sigmoid(cls_boxes[n, cls_targets[m]-1]))      // class cost
//          + sum_k |pred_boxes[n,k] - tgt_boxes[m,k]|           // L1 box cost
//          - IoU(pred_boxes[n], tgt_boxes[m])                   // neg IoU cost
//
// N=16384 preds, M=2048 targets, NCLS=40. Output 128 MiB fp32 -> write-bound
// once per-element redundancy is removed:
//  * sigmoid depends only on (n, class): hoisted to a per-block LDS table
//    (NITER rows x 40 classes), computed once instead of per element.
//  * target boxes/areas/classes register-cached per thread across NITER rows.
//  * IoU division via v_rcp_f32 (1 ulp; threshold is 7.8e-2, huge headroom).

#define NPRED  16384
#define NTGT   2048
#define NCLS   40
#define NITER  16          // n-rows per block
#define MTILES 2           // m-direction tiles: 2 x 1024 columns
#define BLOCK  256

__global__ __launch_bounds__(BLOCK) void matcher_cost_kernel(
    const float*  __restrict__ cls_boxes,    // [NPRED, NCLS]
    const int*    __restrict__ cls_targets,  // [NTGT]
    const float4* __restrict__ pred_boxes,   // [NPRED]
    const float4* __restrict__ tgt_boxes,    // [NTGT]
    float* __restrict__ out)                 // [NPRED, NTGT]
{
    __shared__ float S[NITER * NCLS];        // 1 - sigmoid table, 2.6 KB

    const int mtile = blockIdx.x & (MTILES - 1);
    const int ntile = blockIdx.x / MTILES;
    const int n0 = ntile * NITER;

    // Stage S[r][c] = 1/(1 + exp(cls_boxes[n0+r][c])) — 640 entries, 3 rounds.
    for (int e = threadIdx.x; e < NITER * NCLS; e += BLOCK) {
        int r = e / NCLS;
        int c = e - r * NCLS;
        float x = cls_boxes[(size_t)(n0 + r) * NCLS + c];
        S[e] = __builtin_amdgcn_rcpf(1.0f + __expf(x));
    }

    // Register-cache this thread's 4 consecutive targets.
    const int m4    = mtile * BLOCK + threadIdx.x;   // 0..511
    const int mbase = m4 * 4;
    float4 tb[4];
    float  area2[4];
    int    tc[4];
    #pragma unroll
    for (int j = 0; j < 4; ++j) {
        tb[j]    = tgt_boxes[mbase + j];
        area2[j] = (tb[j].z - tb[j].x) * (tb[j].w - tb[j].y);
        tc[j]    = cls_targets[mbase + j] - 1;       // labels are 1..NCLS
    }

    __syncthreads();

    for (int r = 0; r < NITER; ++r) {
        const int n = n0 + r;
        float4 pb = pred_boxes[n];                   // block-uniform, L1 broadcast
        float area1 = (pb.z - pb.x) * (pb.w - pb.y);
        const float* Srow = S + r * NCLS;

        float4 res;
        float* rv = &res.x;
        #pragma unroll
        for (int j = 0; j < 4; ++j) {
            // IoU
            float lx = fmaxf(pb.x, tb[j].x);
            float ly = fmaxf(pb.y, tb[j].y);
            float rx = fminf(pb.z, tb[j].z);
            float ry = fminf(pb.w, tb[j].w);
            float w  = fmaxf(rx - lx, 0.0f);
            float h  = fmaxf(ry - ly, 0.0f);
            float ov = w * h;
            float uni = fmaxf(area1 + area2[j] - ov, 1e-6f);
            float iou = ov * __builtin_amdgcn_rcpf(uni);

            // L1 box cost (cdist p=1)
            float l1 = fabsf(pb.x - tb[j].x) + fabsf(pb.y - tb[j].y)
                     + fabsf(pb.z - tb[j].z) + fabsf(pb.w - tb[j].w);

            rv[j] = Srow[tc[j]] + l1 - iou;
        }
        *reinterpret_cast<float4*>(out + (size_t)n * NTGT + mbase) = res;
    }
}

extern "C" void kernel_launch(void* const* d_in, const int* in_sizes, int n_in,
                              void* d_out, int out_size, void* d_ws, size_t ws_size,
                              hipStream_t stream) {
    const float*  cls_boxes   = (const float*)d_in[0];
    const int*    cls_targets = (const int*)d_in[1];
    const float4* pred_boxes  = (const float4*)d_in[2];
    const float4* tgt_boxes   = (const float4*)d_in[3];
    float* out = (float*)d_out;

    const int grid = MTILES * (NPRED / NITER);   // 2 * 1024 = 2048 blocks
    matcher_cost_kernel<<<grid, BLOCK, 0, stream>>>(
        cls_boxes, cls_targets, pred_boxes, tgt_boxes, out);
}

// Round 4
// 32.042 us; speedup vs baseline: 2.0107x; 1.0070x over previous
//
#include <hip/hip_runtime.h>

// HungarianMatcher cost matrix:
//   C[n,m] = (1 - sigmoid(cls_boxes[n, cls_targets[m]-1]))      // class cost
//          + sum_k |pred_boxes[n,k] - tgt_boxes[m,k]|           // L1 box cost
//          - IoU(pred_boxes[n], tgt_boxes[m])                   // neg IoU cost
//
// N=16384 preds, M=2048 targets, NCLS=40. Output 128 MiB fp32.
// Structure: block = 16 rows x 1024 cols; thread = 4 cols (float4 store).
//  * sigmoid hoisted to LDS, stored TRANSPOSED [class][row] (stride 20 floats,
//    16B-aligned) so each thread grabs 4 rows of its fixed class with ONE
//    ds_read_b128 -> 16 LDS insts/thread instead of 64, conflict-spread.
//  * rows processed in groups of 4, fully unrolled (16 indep chains, ILP).
//  * res = fma(-ov, rcp(uni), S + l1); rcp via v_rcp_f32 (1 ulp, thr 7.8e-2).
//  * nontemporal stores via clang ext_vector_type (HIP float4 is a class and
//    __builtin_nontemporal_store rejects it -- round-3 compile failure).

#define NPRED  16384
#define NTGT   2048
#define NCLS   40
#define NITER  16          // n-rows per block
#define RG     4           // rows per unrolled group
#define MTILES 2           // m-direction tiles: 2 x 1024 columns
#define BLOCK  256
#define SSTRIDE 20         // floats per class row in ST (16 rows + pad, 80 B)

typedef float f32x4 __attribute__((ext_vector_type(4)));

__global__ __launch_bounds__(BLOCK) void matcher_cost_kernel(
    const float*  __restrict__ cls_boxes,    // [NPRED, NCLS]
    const int*    __restrict__ cls_targets,  // [NTGT]
    const float4* __restrict__ pred_boxes,   // [NPRED]
    const float4* __restrict__ tgt_boxes,    // [NTGT]
    float* __restrict__ out)                 // [NPRED, NTGT]
{
    __shared__ __align__(16) float ST[NCLS * SSTRIDE];   // 3.2 KB, [class][row]

    const int mtile = blockIdx.x & (MTILES - 1);
    const int ntile = blockIdx.x / MTILES;
    const int n0 = ntile * NITER;

    // Stage ST[c][r] = 1/(1 + exp(cls_boxes[n0+r][c])) — 640 entries.
    for (int e = threadIdx.x; e < NCLS * NITER; e += BLOCK) {
        int c = e >> 4;            // 0..39 (NITER == 16)
        int r = e & (NITER - 1);   // 0..15
        float x = cls_boxes[(size_t)(n0 + r) * NCLS + c];
        ST[c * SSTRIDE + r] = __builtin_amdgcn_rcpf(1.0f + __expf(x));
    }

    // Register-cache this thread's 4 consecutive targets.
    const int m4    = mtile * BLOCK + threadIdx.x;   // 0..511
    const int mbase = m4 * 4;
    float4 tb[4];
    float  area2[4];
    int    tcoff[4];                                 // ST offset of class row
    #pragma unroll
    for (int j = 0; j < 4; ++j) {
        tb[j]    = tgt_boxes[mbase + j];
        area2[j] = (tb[j].z - tb[j].x) * (tb[j].w - tb[j].y);
        tcoff[j] = (cls_targets[mbase + j] - 1) * SSTRIDE;  // labels 1..NCLS
    }

    __syncthreads();

    float* orow = out + (size_t)n0 * NTGT + mbase;

    #pragma unroll
    for (int g = 0; g < NITER / RG; ++g) {
        const int nb = n0 + g * RG;

        // One b128 per target class: its sigmoid cost for these 4 rows.
        float sv[4][RG];
        #pragma unroll
        for (int j = 0; j < 4; ++j) {
            f32x4 s4 = *reinterpret_cast<const f32x4*>(&ST[tcoff[j] + g * RG]);
            sv[j][0] = s4.x; sv[j][1] = s4.y; sv[j][2] = s4.z; sv[j][3] = s4.w;
        }

        #pragma unroll
        for (int k = 0; k < RG; ++k) {
            float4 pb = pred_boxes[nb + k];          // block-uniform -> s_load
            float area1 = (pb.z - pb.x) * (pb.w - pb.y);

            f32x4 res;
            #pragma unroll
            for (int j = 0; j < 4; ++j) {
                // IoU
                float lx = fmaxf(pb.x, tb[j].x);
                float ly = fmaxf(pb.y, tb[j].y);
                float rx = fminf(pb.z, tb[j].z);
                float ry = fminf(pb.w, tb[j].w);
                float w  = fmaxf(rx - lx, 0.0f);
                float h  = fmaxf(ry - ly, 0.0f);
                float ov = w * h;
                float uni = fmaxf(area1 + area2[j] - ov, 1e-6f);
                float rc  = __builtin_amdgcn_rcpf(uni);

                // L1 box cost (cdist p=1)
                float l1 = fabsf(pb.x - tb[j].x) + fabsf(pb.y - tb[j].y)
                         + fabsf(pb.z - tb[j].z) + fabsf(pb.w - tb[j].w);

                // class + L1 - IoU, with the IoU mul folded into an FMA
                res[j] = fmaf(-ov, rc, sv[j][k] + l1);
            }
            __builtin_nontemporal_store(res,
                reinterpret_cast<f32x4*>(orow + (size_t)(g * RG + k) * NTGT));
        }
    }
}

extern "C" void kernel_launch(void* const* d_in, const int* in_sizes, int n_in,
                              void* d_out, int out_size, void* d_ws, size_t ws_size,
                              hipStream_t stream) {
    const float*  cls_boxes   = (const float*)d_in[0];
    const int*    cls_targets = (const int*)d_in[1];
    const float4* pred_boxes  = (const float4*)d_in[2];
    const float4* tgt_boxes   = (const float4*)d_in[3];
    float* out = (float*)d_out;

    const int grid = MTILES * (NPRED / NITER);   // 2 * 1024 = 2048 blocks
    matcher_cost_kernel<<<grid, BLOCK, 0, stream>>>(
        cls_boxes, cls_targets, pred_boxes, tgt_boxes, out);
}